// Round 1
// baseline (1813.343 us; speedup 1.0000x reference)
//
#include <hip/hip_runtime.h>
#include <hip/hip_bf16.h>

// ---------------------------------------------------------------------------
// GCN: out = S·gelu(S·gelu(S·X @ W0^T+b0) @ W1^T+b1) @ W2^T + b2
// S = D^-1/2 (I+A) D^-1/2, deg from row-index counts (+1 self loop).
// fp32 everywhere (threshold 1.3e-3 too tight for bf16 MFMA).
// ---------------------------------------------------------------------------

__device__ __forceinline__ float gelu_tanh(float x) {
    // JAX default gelu (approximate=True)
    float x3 = x * x * x;
    float u = 0.7978845608028654f * (x + 0.044715f * x3);
    return 0.5f * x * (1.0f + tanhf(u));
}

__global__ void count_kernel(const int* __restrict__ row, int* __restrict__ cnt, int e) {
    int i = blockIdx.x * blockDim.x + threadIdx.x;
    if (i < e) atomicAdd(&cnt[row[i]], 1);
}

__global__ void rnorm_kernel(const int* __restrict__ cnt, float* __restrict__ rnorm, int n) {
    int i = blockIdx.x * blockDim.x + threadIdx.x;
    if (i < n) rnorm[i] = rsqrtf((float)(cnt[i] + 1));
}

// block-level exclusive scan (1024/block) -> rowptr (exclusive within block) + block sums
__global__ void scan1_kernel(const int* __restrict__ cnt, int* __restrict__ rowptr,
                             int* __restrict__ bsum, int n) {
    __shared__ int s[1024];
    int t = threadIdx.x;
    int i = blockIdx.x * 1024 + t;
    int v = (i < n) ? cnt[i] : 0;
    s[t] = v;
    __syncthreads();
    for (int off = 1; off < 1024; off <<= 1) {
        int x = (t >= off) ? s[t - off] : 0;
        __syncthreads();
        s[t] += x;
        __syncthreads();
    }
    if (i < n) rowptr[i] = s[t] - v;          // exclusive within block
    if (t == 1023) bsum[blockIdx.x] = s[1023]; // block total
}

__global__ void scan2_kernel(int* bsum, int nb) {
    if (threadIdx.x == 0 && blockIdx.x == 0) {
        int a = 0;
        for (int b = 0; b < nb; ++b) { int v = bsum[b]; bsum[b] = a; a += v; }
    }
}

__global__ void scan3_kernel(int* __restrict__ rowptr, const int* __restrict__ bsum, int n, int e) {
    int i = blockIdx.x * blockDim.x + threadIdx.x;
    if (i < n) rowptr[i] += bsum[i >> 10];
    if (i == 0) rowptr[n] = e;
}

__global__ void fill_kernel(const int* __restrict__ row, const int* __restrict__ col,
                            const int* __restrict__ rowptr, int* __restrict__ fillc,
                            const float* __restrict__ rnorm,
                            int* __restrict__ colsorted, float* __restrict__ wsorted, int e) {
    int i = blockIdx.x * blockDim.x + threadIdx.x;
    if (i >= e) return;
    int r = row[i], c = col[i];
    int pos = rowptr[r] + atomicAdd(&fillc[r], 1);
    colsorted[pos] = c;
    wsorted[pos] = rnorm[r] * rnorm[c];
}

__global__ void transpose_kernel(const float* __restrict__ w, float* __restrict__ wt,
                                 int dout, int din, int total) {
    int i = blockIdx.x * blockDim.x + threadIdx.x;
    if (i < total) {
        int k = i / dout, c = i % dout;   // wt[k][c] = w[c][k]
        wt[i] = w[c * din + k];
    }
}

// one wave per row; 64 lanes x float4 = 256 dims
__global__ __launch_bounds__(256) void spmm_kernel(const float4* __restrict__ in,
                                                   float4* __restrict__ out,
                                                   const int* __restrict__ rowptr,
                                                   const int* __restrict__ colsorted,
                                                   const float* __restrict__ wsorted,
                                                   const float* __restrict__ rnorm, int n) {
    int wid = blockIdx.x * 4 + (threadIdx.x >> 6);
    if (wid >= n) return;
    int lane = threadIdx.x & 63;
    float rn = rnorm[wid];
    float sw = rn * rn;                       // self-loop weight = 1/deg
    float4 a = in[(size_t)wid * 64 + lane];
    float4 acc;
    acc.x = sw * a.x; acc.y = sw * a.y; acc.z = sw * a.z; acc.w = sw * a.w;
    int e0 = rowptr[wid], e1 = rowptr[wid + 1];
    for (int e = e0; e < e1; ++e) {
        int c = colsorted[e];
        float w = wsorted[e];
        float4 v = in[(size_t)c * 64 + lane];
        acc.x = fmaf(w, v.x, acc.x);
        acc.y = fmaf(w, v.y, acc.y);
        acc.z = fmaf(w, v.z, acc.z);
        acc.w = fmaf(w, v.w, acc.w);
    }
    out[(size_t)wid * 64 + lane] = acc;
}

// dense: out[N][DO] = in[N][256] @ WT[256][DO] + b, optional gelu.
// block: BM=16 rows x DO cols; thread tile 4 cols x RPT rows.
template <int DO, bool GELU>
__global__ __launch_bounds__(256) void dense_kernel(const float* __restrict__ in,
                                                    const float* __restrict__ wt,
                                                    const float* __restrict__ bias,
                                                    float* __restrict__ out) {
    constexpr int DI = 256, BM = 16, KC = 64;
    constexpr int TC = DO / 4;      // col-thread count (64 or 32)
    constexpr int TR = 256 / TC;    // row-thread count (4 or 8)
    constexpr int RPT = BM / TR;    // rows per thread (4 or 2)
    __shared__ float s_inT[DI][BM + 1];   // transposed input tile (pad: conflict-free writes)
    __shared__ float s_w[KC][DO];         // weight chunk (flat copy, conflict-free)

    int t = threadIdx.x;
    int row0 = blockIdx.x * BM;

    // stage input tile transposed: coalesced global reads, stride-17 LDS writes
#pragma unroll
    for (int i = 0; i < (BM * DI) / 256; ++i) {
        int idx = t + i * 256;
        int r = idx >> 8, k = idx & 255;
        s_inT[k][r] = in[(size_t)row0 * DI + idx];
    }

    int tc = t % TC, tr = t / TC;
    int c0 = tc * 4, r0 = tr * RPT;
    float acc[RPT][4];
#pragma unroll
    for (int j = 0; j < RPT; ++j)
#pragma unroll
        for (int q = 0; q < 4; ++q) acc[j][q] = 0.0f;

    for (int k0 = 0; k0 < DI; k0 += KC) {
        __syncthreads();
        // stage weight chunk: flat float4 copy
        const float4* wtv = (const float4*)(wt + (size_t)k0 * DO);
        float4* swv = (float4*)s_w;
#pragma unroll
        for (int i = 0; i < (KC * DO) / (256 * 4); ++i) swv[t + i * 256] = wtv[t + i * 256];
        __syncthreads();

#pragma unroll 8
        for (int kk = 0; kk < KC; ++kk) {
            float4 w4 = *(const float4*)&s_w[kk][c0];
            float iv[RPT];
#pragma unroll
            for (int j = 0; j < RPT; ++j) iv[j] = s_inT[k0 + kk][r0 + j];
#pragma unroll
            for (int j = 0; j < RPT; ++j) {
                acc[j][0] = fmaf(iv[j], w4.x, acc[j][0]);
                acc[j][1] = fmaf(iv[j], w4.y, acc[j][1]);
                acc[j][2] = fmaf(iv[j], w4.z, acc[j][2]);
                acc[j][3] = fmaf(iv[j], w4.w, acc[j][3]);
            }
        }
    }

#pragma unroll
    for (int j = 0; j < RPT; ++j) {
        int r = row0 + r0 + j;
        float4 o;
        float bx = bias[c0], by = bias[c0 + 1], bz = bias[c0 + 2], bw = bias[c0 + 3];
        o.x = acc[j][0] + bx; o.y = acc[j][1] + by; o.z = acc[j][2] + bz; o.w = acc[j][3] + bw;
        if (GELU) {
            o.x = gelu_tanh(o.x); o.y = gelu_tanh(o.y);
            o.z = gelu_tanh(o.z); o.w = gelu_tanh(o.w);
        }
        *(float4*)&out[(size_t)r * DO + c0] = o;
    }
}

extern "C" void kernel_launch(void* const* d_in, const int* in_sizes, int n_in,
                              void* d_out, int out_size, void* d_ws, size_t ws_size,
                              hipStream_t stream) {
    const float* X  = (const float*)d_in[0];
    const int* row  = (const int*)d_in[1];
    const int* col  = (const int*)d_in[2];
    const float* W0 = (const float*)d_in[3];
    const float* b0 = (const float*)d_in[4];
    const float* W1 = (const float*)d_in[5];
    const float* b1 = (const float*)d_in[6];
    const float* W2 = (const float*)d_in[7];
    const float* b2 = (const float*)d_in[8];

    int n = in_sizes[0] / 256;   // 100000
    int e = in_sizes[1];         // 1600000

    char* ws = (char*)d_ws;
    size_t off = 0;
    auto alloc = [&](size_t bytes) {
        void* p = ws + off;
        off += (bytes + 255) & ~(size_t)255;
        return p;
    };
    float* A         = (float*)alloc((size_t)n * 256 * 4);
    float* B         = (float*)alloc((size_t)n * 256 * 4);
    float* WT0       = (float*)alloc(256 * 256 * 4);
    float* WT1       = (float*)alloc(256 * 256 * 4);
    float* WT2       = (float*)alloc(256 * 128 * 4);
    int*   cnt       = (int*)alloc((size_t)n * 4);
    int*   fillc     = (int*)alloc((size_t)n * 4);
    float* rnorm     = (float*)alloc((size_t)n * 4);
    int*   rowptr    = (int*)alloc(((size_t)n + 1) * 4);
    int*   bsum      = (int*)alloc(512);
    int*   colsorted = (int*)alloc((size_t)e * 4);
    float* wsorted   = (float*)alloc((size_t)e * 4);

    hipMemsetAsync(cnt, 0, (size_t)n * 4, stream);
    hipMemsetAsync(fillc, 0, (size_t)n * 4, stream);

    int gE = (e + 255) / 256;
    int gN = (n + 255) / 256;
    int nb = (n + 1023) / 1024;

    count_kernel<<<gE, 256, 0, stream>>>(row, cnt, e);
    rnorm_kernel<<<gN, 256, 0, stream>>>(cnt, rnorm, n);
    scan1_kernel<<<nb, 1024, 0, stream>>>(cnt, rowptr, bsum, n);
    scan2_kernel<<<1, 64, 0, stream>>>(bsum, nb);
    scan3_kernel<<<gN, 256, 0, stream>>>(rowptr, bsum, n, e);
    fill_kernel<<<gE, 256, 0, stream>>>(row, col, rowptr, fillc, rnorm, colsorted, wsorted, e);

    transpose_kernel<<<(256 * 256) / 256, 256, 0, stream>>>(W0, WT0, 256, 256, 256 * 256);
    transpose_kernel<<<(256 * 256) / 256, 256, 0, stream>>>(W1, WT1, 256, 256, 256 * 256);
    transpose_kernel<<<(256 * 128) / 256, 256, 0, stream>>>(W2, WT2, 128, 256, 256 * 128);

    int gS = (n + 3) / 4;
    int gD = n / 16;   // 100000 % 16 == 0

    spmm_kernel<<<gS, 256, 0, stream>>>((const float4*)X, (float4*)A, rowptr, colsorted, wsorted, rnorm, n);
    dense_kernel<256, true><<<gD, 256, 0, stream>>>(A, WT0, b0, B);
    spmm_kernel<<<gS, 256, 0, stream>>>((const float4*)B, (float4*)A, rowptr, colsorted, wsorted, rnorm, n);
    dense_kernel<256, true><<<gD, 256, 0, stream>>>(A, WT1, b1, B);
    spmm_kernel<<<gS, 256, 0, stream>>>((const float4*)B, (float4*)A, rowptr, colsorted, wsorted, rnorm, n);
    dense_kernel<128, false><<<gD, 256, 0, stream>>>(A, WT2, b2, (float*)d_out);
}

// Round 2
// 1248.904 us; speedup vs baseline: 1.4519x; 1.4519x over previous
//
#include <hip/hip_runtime.h>
#include <hip/hip_bf16.h>

// ---------------------------------------------------------------------------
// GCN restructured via associativity:  spmm(H) @ W == spmm(H @ W)
//   D0 = X @ W0T          ; A = gelu(spmm(D0) + b0)
//   D1 = A @ W1T          ; B = gelu(spmm(D1) + b1)
//   D2 = B @ W2T (128-w)  ; out = spmm(D2) + b2     <- final spmm 128-wide
// fp32 everywhere (threshold 1.3e-3 too tight for bf16 MFMA).
// ---------------------------------------------------------------------------

__device__ __forceinline__ float gelu_fast(float x) {
    // 0.5x(1+tanh(u)) == x * sigmoid(2u); one hw exp instead of sw tanh
    float u = 0.7978845608028654f * (x + 0.044715f * x * x * x);
    return x / (1.0f + __expf(-2.0f * u));
}

__global__ void count_kernel(const int* __restrict__ row, int* __restrict__ cnt, int e) {
    int i = blockIdx.x * blockDim.x + threadIdx.x;
    if (i < e) atomicAdd(&cnt[row[i]], 1);
}

__global__ void rnorm_kernel(const int* __restrict__ cnt, float* __restrict__ rnorm, int n) {
    int i = blockIdx.x * blockDim.x + threadIdx.x;
    if (i < n) rnorm[i] = rsqrtf((float)(cnt[i] + 1));
}

__global__ void scan1_kernel(const int* __restrict__ cnt, int* __restrict__ rowptr,
                             int* __restrict__ bsum, int n) {
    __shared__ int s[1024];
    int t = threadIdx.x;
    int i = blockIdx.x * 1024 + t;
    int v = (i < n) ? cnt[i] : 0;
    s[t] = v;
    __syncthreads();
    for (int off = 1; off < 1024; off <<= 1) {
        int x = (t >= off) ? s[t - off] : 0;
        __syncthreads();
        s[t] += x;
        __syncthreads();
    }
    if (i < n) rowptr[i] = s[t] - v;
    if (t == 1023) bsum[blockIdx.x] = s[1023];
}

__global__ void scan2_kernel(int* bsum, int nb) {
    if (threadIdx.x == 0 && blockIdx.x == 0) {
        int a = 0;
        for (int b = 0; b < nb; ++b) { int v = bsum[b]; bsum[b] = a; a += v; }
    }
}

__global__ void scan3_kernel(int* __restrict__ rowptr, const int* __restrict__ bsum, int n, int e) {
    int i = blockIdx.x * blockDim.x + threadIdx.x;
    if (i < n) rowptr[i] += bsum[i >> 10];
    if (i == 0) rowptr[n] = e;
}

__global__ void fill_kernel(const int* __restrict__ row, const int* __restrict__ col,
                            const int* __restrict__ rowptr, int* __restrict__ fillc,
                            const float* __restrict__ rnorm,
                            int2* __restrict__ meta, int e) {
    int i = blockIdx.x * blockDim.x + threadIdx.x;
    if (i >= e) return;
    int r = row[i], c = col[i];
    int pos = rowptr[r] + atomicAdd(&fillc[r], 1);
    float w = rnorm[r] * rnorm[c];
    meta[pos] = make_int2(c, __float_as_int(w));
}

__global__ void transpose_kernel(const float* __restrict__ w, float* __restrict__ wt,
                                 int dout, int din, int total) {
    int i = blockIdx.x * blockDim.x + threadIdx.x;
    if (i < total) {
        int k = i / dout, c = i % dout;   // wt[k][c] = w[c][k]
        wt[i] = w[c * din + k];
    }
}

template <int WPL> struct VecT;
template <> struct VecT<4> { using T = float4; };
template <> struct VecT<2> { using T = float2; };

// one wave per row; 64 lanes x WPL floats per row. Bias (+ optional gelu) fused.
template <int WPL, bool GELU>
__global__ __launch_bounds__(256) void spmm_kernel(const float* __restrict__ in,
                                                   float* __restrict__ out,
                                                   const int* __restrict__ rowptr,
                                                   const int2* __restrict__ meta,
                                                   const float* __restrict__ rnorm,
                                                   const float* __restrict__ bias, int n) {
    using vec_t = typename VecT<WPL>::T;
    constexpr int RW = 64 * WPL;
    int wid = blockIdx.x * 4 + (threadIdx.x >> 6);
    if (wid >= n) return;
    int lane = threadIdx.x & 63;
    const float* lanebase = in + lane * WPL;

    float rn = rnorm[wid];
    float sw = rn * rn;   // self-loop weight
    float acc[WPL];
    {
        vec_t a = *(const vec_t*)(lanebase + (size_t)wid * RW);
        const float* ap = (const float*)&a;
#pragma unroll
        for (int q = 0; q < WPL; ++q) acc[q] = sw * ap[q];
    }

    int e0 = rowptr[wid], e1 = rowptr[wid + 1];
    int e = e0;
    for (; e + 4 <= e1; e += 4) {
        int2 m0 = meta[e], m1 = meta[e + 1], m2 = meta[e + 2], m3 = meta[e + 3];
        vec_t v0 = *(const vec_t*)(lanebase + (size_t)m0.x * RW);
        vec_t v1 = *(const vec_t*)(lanebase + (size_t)m1.x * RW);
        vec_t v2 = *(const vec_t*)(lanebase + (size_t)m2.x * RW);
        vec_t v3 = *(const vec_t*)(lanebase + (size_t)m3.x * RW);
        float w0 = __int_as_float(m0.y), w1 = __int_as_float(m1.y);
        float w2 = __int_as_float(m2.y), w3 = __int_as_float(m3.y);
        const float* p0 = (const float*)&v0; const float* p1 = (const float*)&v1;
        const float* p2 = (const float*)&v2; const float* p3 = (const float*)&v3;
#pragma unroll
        for (int q = 0; q < WPL; ++q) {
            acc[q] = fmaf(w0, p0[q], acc[q]);
            acc[q] = fmaf(w1, p1[q], acc[q]);
            acc[q] = fmaf(w2, p2[q], acc[q]);
            acc[q] = fmaf(w3, p3[q], acc[q]);
        }
    }
    for (; e < e1; ++e) {
        int2 m = meta[e];
        vec_t v = *(const vec_t*)(lanebase + (size_t)m.x * RW);
        float w = __int_as_float(m.y);
        const float* p = (const float*)&v;
#pragma unroll
        for (int q = 0; q < WPL; ++q) acc[q] = fmaf(w, p[q], acc[q]);
    }

    vec_t bv = *(const vec_t*)(bias + lane * WPL);
    const float* bp = (const float*)&bv;
    vec_t o;
    float* op = (float*)&o;
#pragma unroll
    for (int q = 0; q < WPL; ++q) {
        float x = acc[q] + bp[q];
        op[q] = GELU ? gelu_fast(x) : x;
    }
    *(vec_t*)(out + (size_t)wid * RW + lane * WPL) = o;
}

// dense: out[N][DO] = in[N][256] @ WT[256][DO]. No bias/gelu (fused into spmm).
// BM=32 rows staged once in LDS (no k-loop barriers); weights streamed from L2.
template <int DO>
__global__ __launch_bounds__(256, 2) void dense_kernel(const float* __restrict__ in,
                                                       const float* __restrict__ wt,
                                                       float* __restrict__ out) {
    constexpr int BM = 32;
    constexpr int TC = DO / 4;     // 64 or 32 col-threads
    constexpr int TR = 256 / TC;   // 4 or 8 row-threads
    constexpr int RPT = BM / TR;   // 8 or 4 rows per thread
    constexpr int LDR = 256 + 4;   // padded row stride (floats), float4-aligned
    __shared__ float s_in[BM * LDR];

    int t = threadIdx.x;
    int row0 = blockIdx.x * BM;

    // stage 32x256 input tile: coalesced float4 reads, conflict-free float4 writes
    const float4* gin = (const float4*)(in + (size_t)row0 * 256);
#pragma unroll
    for (int i = 0; i < (BM * 64) / 256; ++i) {   // 8 iters
        int idx = t + i * 256;
        int r = idx >> 6, k4 = idx & 63;
        *(float4*)&s_in[r * LDR + k4 * 4] = gin[idx];
    }
    __syncthreads();

    int tc = t % TC, tr = t / TC;
    int c0 = tc * 4;
    int r0 = tr * RPT;
    const float* sbase = &s_in[r0 * LDR];
    const float4* wrow = (const float4*)wt + tc;   // wt[k][c0..c0+3]

    float acc[RPT][4];
#pragma unroll
    for (int j = 0; j < RPT; ++j)
#pragma unroll
        for (int q = 0; q < 4; ++q) acc[j][q] = 0.0f;

#pragma unroll 4
    for (int k = 0; k < 256; ++k) {
        float4 w4 = wrow[k * TC];          // coalesced 1KB/wave, L2-hit
        float iv[RPT];
#pragma unroll
        for (int j = 0; j < RPT; ++j) iv[j] = sbase[j * LDR + k];  // LDS broadcast
#pragma unroll
        for (int j = 0; j < RPT; ++j) {
            acc[j][0] = fmaf(iv[j], w4.x, acc[j][0]);
            acc[j][1] = fmaf(iv[j], w4.y, acc[j][1]);
            acc[j][2] = fmaf(iv[j], w4.z, acc[j][2]);
            acc[j][3] = fmaf(iv[j], w4.w, acc[j][3]);
        }
    }

#pragma unroll
    for (int j = 0; j < RPT; ++j) {
        *(float4*)&out[(size_t)(row0 + r0 + j) * DO + c0] =
            make_float4(acc[j][0], acc[j][1], acc[j][2], acc[j][3]);
    }
}

extern "C" void kernel_launch(void* const* d_in, const int* in_sizes, int n_in,
                              void* d_out, int out_size, void* d_ws, size_t ws_size,
                              hipStream_t stream) {
    const float* X  = (const float*)d_in[0];
    const int* row  = (const int*)d_in[1];
    const int* col  = (const int*)d_in[2];
    const float* W0 = (const float*)d_in[3];
    const float* b0 = (const float*)d_in[4];
    const float* W1 = (const float*)d_in[5];
    const float* b1 = (const float*)d_in[6];
    const float* W2 = (const float*)d_in[7];
    const float* b2 = (const float*)d_in[8];

    int n = in_sizes[0] / 256;   // 100000
    int e = in_sizes[1];         // 1600000

    char* ws = (char*)d_ws;
    size_t off = 0;
    auto alloc = [&](size_t bytes) {
        void* p = ws + off;
        off += (bytes + 255) & ~(size_t)255;
        return p;
    };
    float* A      = (float*)alloc((size_t)n * 256 * 4);
    float* B      = (float*)alloc((size_t)n * 256 * 4);
    float* WT0    = (float*)alloc(256 * 256 * 4);
    float* WT1    = (float*)alloc(256 * 256 * 4);
    float* WT2    = (float*)alloc(256 * 128 * 4);
    int*   cnt    = (int*)alloc((size_t)n * 4);
    int*   fillc  = (int*)alloc((size_t)n * 4);
    float* rnorm  = (float*)alloc((size_t)n * 4);
    int*   rowptr = (int*)alloc(((size_t)n + 1) * 4);
    int*   bsum   = (int*)alloc(512);
    int2*  meta   = (int2*)alloc((size_t)e * 8);

    hipMemsetAsync(cnt, 0, (size_t)n * 4, stream);
    hipMemsetAsync(fillc, 0, (size_t)n * 4, stream);

    int gE = (e + 255) / 256;
    int gN = (n + 255) / 256;
    int nb = (n + 1023) / 1024;

    count_kernel<<<gE, 256, 0, stream>>>(row, cnt, e);
    rnorm_kernel<<<gN, 256, 0, stream>>>(cnt, rnorm, n);
    scan1_kernel<<<nb, 1024, 0, stream>>>(cnt, rowptr, bsum, n);
    scan2_kernel<<<1, 64, 0, stream>>>(bsum, nb);
    scan3_kernel<<<gN, 256, 0, stream>>>(rowptr, bsum, n, e);
    fill_kernel<<<gE, 256, 0, stream>>>(row, col, rowptr, fillc, rnorm, meta, e);

    transpose_kernel<<<(256 * 256) / 256, 256, 0, stream>>>(W0, WT0, 256, 256, 256 * 256);
    transpose_kernel<<<(256 * 256) / 256, 256, 0, stream>>>(W1, WT1, 256, 256, 256 * 256);
    transpose_kernel<<<(256 * 128) / 256, 256, 0, stream>>>(W2, WT2, 128, 256, 256 * 128);

    int gS = (n + 3) / 4;      // spmm: 4 waves/block, 1 row/wave
    int gD = n / 32;           // dense: 32 rows/block (100000 % 32 == 0)

    // D0 = X @ W0T ; A = gelu(spmm(D0) + b0)
    dense_kernel<256><<<gD, 256, 0, stream>>>(X, WT0, A);
    spmm_kernel<4, true><<<gS, 256, 0, stream>>>(A, B, rowptr, meta, rnorm, b0, n);
    // D1 = B @ W1T ; A = gelu(spmm(D1) + b1)
    dense_kernel<256><<<gD, 256, 0, stream>>>(B, WT1, A);
    spmm_kernel<4, true><<<gS, 256, 0, stream>>>(A, B, rowptr, meta, rnorm, b1, n);
    // D2 = B @ W2T (128 wide) ; out = spmm(D2) + b2
    dense_kernel<128><<<gD, 256, 0, stream>>>(B, WT2, A);
    spmm_kernel<2, false><<<gS, 256, 0, stream>>>(A, (float*)d_out, rowptr, meta, rnorm, b2, n);
}

// Round 4
// 1240.538 us; speedup vs baseline: 1.4617x; 1.0067x over previous
//
#include <hip/hip_runtime.h>
#include <hip/hip_bf16.h>

// ---------------------------------------------------------------------------
// GCN restructured via associativity:  spmm(H) @ W == spmm(H @ W)
//   D0 = X @ W0T          ; A = gelu(spmm(D0) + b0)
//   D1 = A @ W1T          ; B = gelu(spmm(D1) + b1)
//   D2 = B @ W2T (128-w)  ; out = spmm(D2) + b2     <- final spmm 128-wide
// fp32 everywhere. Cache policy: gathered buffers (dense outputs) stay
// L3-resident; all streaming traffic (dense inputs, spmm outputs) is
// non-temporal so the 256MB Infinity Cache doesn't thrash.
// ---------------------------------------------------------------------------

typedef float f32x4 __attribute__((ext_vector_type(4)));
typedef float f32x2 __attribute__((ext_vector_type(2)));

__device__ __forceinline__ float gelu_fast(float x) {
    // 0.5x(1+tanh(u)) == x * sigmoid(2u); one hw exp instead of sw tanh
    float u = 0.7978845608028654f * (x + 0.044715f * x * x * x);
    return x / (1.0f + __expf(-2.0f * u));
}

__global__ void count_kernel(const int* __restrict__ row, int* __restrict__ cnt, int e) {
    int i = blockIdx.x * blockDim.x + threadIdx.x;
    if (i < e) atomicAdd(&cnt[row[i]], 1);
}

__global__ void rnorm_kernel(const int* __restrict__ cnt, float* __restrict__ rnorm, int n) {
    int i = blockIdx.x * blockDim.x + threadIdx.x;
    if (i < n) rnorm[i] = rsqrtf((float)(cnt[i] + 1));
}

__global__ void scan1_kernel(const int* __restrict__ cnt, int* __restrict__ rowptr,
                             int* __restrict__ bsum, int n) {
    __shared__ int s[1024];
    int t = threadIdx.x;
    int i = blockIdx.x * 1024 + t;
    int v = (i < n) ? cnt[i] : 0;
    s[t] = v;
    __syncthreads();
    for (int off = 1; off < 1024; off <<= 1) {
        int x = (t >= off) ? s[t - off] : 0;
        __syncthreads();
        s[t] += x;
        __syncthreads();
    }
    if (i < n) rowptr[i] = s[t] - v;
    if (t == 1023) bsum[blockIdx.x] = s[1023];
}

__global__ void scan2_kernel(int* bsum, int nb) {
    if (threadIdx.x == 0 && blockIdx.x == 0) {
        int a = 0;
        for (int b = 0; b < nb; ++b) { int v = bsum[b]; bsum[b] = a; a += v; }
    }
}

__global__ void scan3_kernel(int* __restrict__ rowptr, const int* __restrict__ bsum, int n, int e) {
    int i = blockIdx.x * blockDim.x + threadIdx.x;
    if (i < n) rowptr[i] += bsum[i >> 10];
    if (i == 0) rowptr[n] = e;
}

__global__ void fill_kernel(const int* __restrict__ row, const int* __restrict__ col,
                            const int* __restrict__ rowptr, int* __restrict__ fillc,
                            const float* __restrict__ rnorm,
                            int2* __restrict__ meta, int e) {
    int i = blockIdx.x * blockDim.x + threadIdx.x;
    if (i >= e) return;
    int r = row[i], c = col[i];
    int pos = rowptr[r] + atomicAdd(&fillc[r], 1);
    float w = rnorm[r] * rnorm[c];
    meta[pos] = make_int2(c, __float_as_int(w));
}

__global__ void transpose_kernel(const float* __restrict__ w, float* __restrict__ wt,
                                 int dout, int din, int total) {
    int i = blockIdx.x * blockDim.x + threadIdx.x;
    if (i < total) {
        int k = i / dout, c = i % dout;   // wt[k][c] = w[c][k]
        wt[i] = w[c * din + k];
    }
}

template <int WPL> struct VecT;
template <> struct VecT<4> { using T = f32x4; };
template <> struct VecT<2> { using T = f32x2; };

// one wave per row; 64 lanes x WPL floats. Bias (+ optional gelu) fused.
// 8 gathers in flight per iteration; output stores non-temporal.
template <int WPL, bool GELU>
__global__ __launch_bounds__(256) void spmm_kernel(const float* __restrict__ in,
                                                   float* __restrict__ out,
                                                   const int* __restrict__ rowptr,
                                                   const int2* __restrict__ meta,
                                                   const float* __restrict__ rnorm,
                                                   const float* __restrict__ bias, int n) {
    using vec_t = typename VecT<WPL>::T;
    constexpr int RW = 64 * WPL;
    int wid = blockIdx.x * 4 + (threadIdx.x >> 6);
    if (wid >= n) return;
    int lane = threadIdx.x & 63;
    const float* lanebase = in + lane * WPL;

    float rn = rnorm[wid];
    float sw = rn * rn;   // self-loop weight
    float acc[WPL];
    {
        vec_t a = *(const vec_t*)(lanebase + (size_t)wid * RW);
#pragma unroll
        for (int q = 0; q < WPL; ++q) acc[q] = sw * a[q];
    }

    int e0 = rowptr[wid], e1 = rowptr[wid + 1];
    int e = e0;
    for (; e + 8 <= e1; e += 8) {
        int2 m[8];
#pragma unroll
        for (int u = 0; u < 8; ++u) m[u] = meta[e + u];
        vec_t v[8];
#pragma unroll
        for (int u = 0; u < 8; ++u) v[u] = *(const vec_t*)(lanebase + (size_t)m[u].x * RW);
#pragma unroll
        for (int u = 0; u < 8; ++u) {
            float w = __int_as_float(m[u].y);
#pragma unroll
            for (int q = 0; q < WPL; ++q) acc[q] = fmaf(w, v[u][q], acc[q]);
        }
    }
    for (; e + 2 <= e1; e += 2) {
        int2 m0 = meta[e], m1 = meta[e + 1];
        vec_t v0 = *(const vec_t*)(lanebase + (size_t)m0.x * RW);
        vec_t v1 = *(const vec_t*)(lanebase + (size_t)m1.x * RW);
        float w0 = __int_as_float(m0.y), w1 = __int_as_float(m1.y);
#pragma unroll
        for (int q = 0; q < WPL; ++q) {
            acc[q] = fmaf(w0, v0[q], acc[q]);
            acc[q] = fmaf(w1, v1[q], acc[q]);
        }
    }
    if (e < e1) {
        int2 m = meta[e];
        vec_t v = *(const vec_t*)(lanebase + (size_t)m.x * RW);
        float w = __int_as_float(m.y);
#pragma unroll
        for (int q = 0; q < WPL; ++q) acc[q] = fmaf(w, v[q], acc[q]);
    }

    vec_t bv = *(const vec_t*)(bias + lane * WPL);
    vec_t o;
#pragma unroll
    for (int q = 0; q < WPL; ++q) {
        float x = acc[q] + bv[q];
        o[q] = GELU ? gelu_fast(x) : x;
    }
    __builtin_nontemporal_store(o, (vec_t*)(out + (size_t)wid * RW + lane * WPL));
}

// dense: out[N][DO] = in[N][256] @ WT[256][DO]. No bias/gelu (fused into spmm).
// BM=32 rows staged once in LDS (no k-loop barriers); weights streamed from L2.
// Input loads non-temporal (read-once); output stores normal (gathered next).
template <int DO>
__global__ __launch_bounds__(256, 4) void dense_kernel(const float* __restrict__ in,
                                                       const float* __restrict__ wt,
                                                       float* __restrict__ out) {
    constexpr int BM = 32;
    constexpr int TC = DO / 4;     // 64 or 32 col-threads
    constexpr int TR = 256 / TC;   // 4 or 8 row-threads
    constexpr int RPT = BM / TR;   // 8 or 4 rows per thread
    constexpr int LDR = 256 + 4;   // padded row stride (floats), float4-aligned
    __shared__ float s_in[BM * LDR];

    int t = threadIdx.x;
    int row0 = blockIdx.x * BM;

    const f32x4* gin = (const f32x4*)(in + (size_t)row0 * 256);
#pragma unroll
    for (int i = 0; i < (BM * 64) / 256; ++i) {   // 8 iters
        int idx = t + i * 256;
        int r = idx >> 6, k4 = idx & 63;
        f32x4 val = __builtin_nontemporal_load(gin + idx);
        *(f32x4*)&s_in[r * LDR + k4 * 4] = val;
    }
    __syncthreads();

    int tc = t % TC, tr = t / TC;
    int c0 = tc * 4;
    int r0 = tr * RPT;
    const float* sbase = &s_in[r0 * LDR];
    const f32x4* wrow = (const f32x4*)wt + tc;   // wt[k][c0..c0+3]

    float acc[RPT][4];
#pragma unroll
    for (int j = 0; j < RPT; ++j)
#pragma unroll
        for (int q = 0; q < 4; ++q) acc[j][q] = 0.0f;

#pragma unroll 4
    for (int k = 0; k < 256; ++k) {
        f32x4 w4 = wrow[k * TC];           // coalesced, L2-resident
        float iv[RPT];
#pragma unroll
        for (int j = 0; j < RPT; ++j) iv[j] = sbase[j * LDR + k];  // LDS broadcast
#pragma unroll
        for (int j = 0; j < RPT; ++j) {
            acc[j][0] = fmaf(iv[j], w4.x, acc[j][0]);
            acc[j][1] = fmaf(iv[j], w4.y, acc[j][1]);
            acc[j][2] = fmaf(iv[j], w4.z, acc[j][2]);
            acc[j][3] = fmaf(iv[j], w4.w, acc[j][3]);
        }
    }

#pragma unroll
    for (int j = 0; j < RPT; ++j) {
        f32x4 o = { acc[j][0], acc[j][1], acc[j][2], acc[j][3] };
        *(f32x4*)&out[(size_t)(row0 + r0 + j) * DO + c0] = o;
    }
}

extern "C" void kernel_launch(void* const* d_in, const int* in_sizes, int n_in,
                              void* d_out, int out_size, void* d_ws, size_t ws_size,
                              hipStream_t stream) {
    const float* X  = (const float*)d_in[0];
    const int* row  = (const int*)d_in[1];
    const int* col  = (const int*)d_in[2];
    const float* W0 = (const float*)d_in[3];
    const float* b0 = (const float*)d_in[4];
    const float* W1 = (const float*)d_in[5];
    const float* b1 = (const float*)d_in[6];
    const float* W2 = (const float*)d_in[7];
    const float* b2 = (const float*)d_in[8];

    int n = in_sizes[0] / 256;   // 100000
    int e = in_sizes[1];         // 1600000

    char* ws = (char*)d_ws;
    size_t off = 0;
    auto alloc = [&](size_t bytes) {
        void* p = ws + off;
        off += (bytes + 255) & ~(size_t)255;
        return p;
    };
    float* A      = (float*)alloc((size_t)n * 256 * 4);
    float* B      = (float*)alloc((size_t)n * 256 * 4);
    float* WT0    = (float*)alloc(256 * 256 * 4);
    float* WT1    = (float*)alloc(256 * 256 * 4);
    float* WT2    = (float*)alloc(256 * 128 * 4);
    int*   cnt    = (int*)alloc((size_t)n * 4);
    int*   fillc  = (int*)alloc((size_t)n * 4);
    float* rnorm  = (float*)alloc((size_t)n * 4);
    int*   rowptr = (int*)alloc(((size_t)n + 1) * 4);
    int*   bsum   = (int*)alloc(512);
    int2*  meta   = (int2*)alloc((size_t)e * 8);

    (void)hipMemsetAsync(cnt, 0, (size_t)n * 4, stream);
    (void)hipMemsetAsync(fillc, 0, (size_t)n * 4, stream);

    int gE = (e + 255) / 256;
    int gN = (n + 255) / 256;
    int nb = (n + 1023) / 1024;

    count_kernel<<<gE, 256, 0, stream>>>(row, cnt, e);
    rnorm_kernel<<<gN, 256, 0, stream>>>(cnt, rnorm, n);
    scan1_kernel<<<nb, 1024, 0, stream>>>(cnt, rowptr, bsum, n);
    scan2_kernel<<<1, 64, 0, stream>>>(bsum, nb);
    scan3_kernel<<<gN, 256, 0, stream>>>(rowptr, bsum, n, e);
    fill_kernel<<<gE, 256, 0, stream>>>(row, col, rowptr, fillc, rnorm, meta, e);

    transpose_kernel<<<(256 * 256) / 256, 256, 0, stream>>>(W0, WT0, 256, 256, 256 * 256);
    transpose_kernel<<<(256 * 256) / 256, 256, 0, stream>>>(W1, WT1, 256, 256, 256 * 256);
    transpose_kernel<<<(256 * 128) / 256, 256, 0, stream>>>(W2, WT2, 128, 256, 256 * 128);

    int gS = (n + 3) / 4;      // spmm: 4 waves/block, 1 row/wave
    int gD = n / 32;           // dense: 32 rows/block (100000 % 32 == 0)

    // D0 = X @ W0T ; A = gelu(spmm(D0) + b0)
    dense_kernel<256><<<gD, 256, 0, stream>>>(X, WT0, A);
    spmm_kernel<4, true><<<gS, 256, 0, stream>>>(A, B, rowptr, meta, rnorm, b0, n);
    // D1 = B @ W1T ; A = gelu(spmm(D1) + b1)
    dense_kernel<256><<<gD, 256, 0, stream>>>(B, WT1, A);
    spmm_kernel<4, true><<<gS, 256, 0, stream>>>(A, B, rowptr, meta, rnorm, b1, n);
    // D2 = B @ W2T (128 wide) ; out = spmm(D2) + b2
    dense_kernel<128><<<gD, 256, 0, stream>>>(B, WT2, A);
    spmm_kernel<2, false><<<gS, 256, 0, stream>>>(A, (float*)d_out, rowptr, meta, rnorm, b2, n);
}

// Round 5
// 1233.165 us; speedup vs baseline: 1.4705x; 1.0060x over previous
//
#include <hip/hip_runtime.h>
#include <hip/hip_bf16.h>

// ---------------------------------------------------------------------------
// GCN restructured via associativity:  spmm(H) @ W == spmm(H @ W)
//   D0 = X @ W0T          ; A = gelu(spmm(D0) + b0)
//   D1 = A @ W1T          ; B = gelu(spmm(D1) + b1)
//   D2 = B @ W2T (128-w)  ; out = spmm(D2) + b2     <- final spmm 128-wide
// fp32 everywhere (bf16 intermediate would blow the 1.3e-3 threshold).
// dense: col-partitioned waves -> block reads each weight row ONCE per k
// (was 4x -> 3.2GB L2 traffic, the old bottleneck).
// ---------------------------------------------------------------------------

typedef float f32x4 __attribute__((ext_vector_type(4)));
typedef float f32x2 __attribute__((ext_vector_type(2)));

__device__ __forceinline__ float gelu_fast(float x) {
    // 0.5x(1+tanh(u)) == x * sigmoid(2u); one hw exp instead of sw tanh
    float u = 0.7978845608028654f * (x + 0.044715f * x * x * x);
    return x / (1.0f + __expf(-2.0f * u));
}

__global__ void count_kernel(const int* __restrict__ row, int* __restrict__ cnt, int e) {
    int i = blockIdx.x * blockDim.x + threadIdx.x;
    if (i < e) atomicAdd(&cnt[row[i]], 1);
}

__global__ void rnorm_kernel(const int* __restrict__ cnt, float* __restrict__ rnorm, int n) {
    int i = blockIdx.x * blockDim.x + threadIdx.x;
    if (i < n) rnorm[i] = rsqrtf((float)(cnt[i] + 1));
}

__global__ void scan1_kernel(const int* __restrict__ cnt, int* __restrict__ rowptr,
                             int* __restrict__ bsum, int n) {
    __shared__ int s[1024];
    int t = threadIdx.x;
    int i = blockIdx.x * 1024 + t;
    int v = (i < n) ? cnt[i] : 0;
    s[t] = v;
    __syncthreads();
    for (int off = 1; off < 1024; off <<= 1) {
        int x = (t >= off) ? s[t - off] : 0;
        __syncthreads();
        s[t] += x;
        __syncthreads();
    }
    if (i < n) rowptr[i] = s[t] - v;
    if (t == 1023) bsum[blockIdx.x] = s[1023];
}

__global__ void scan2_kernel(int* bsum, int nb) {
    if (threadIdx.x == 0 && blockIdx.x == 0) {
        int a = 0;
        for (int b = 0; b < nb; ++b) { int v = bsum[b]; bsum[b] = a; a += v; }
    }
}

__global__ void scan3_kernel(int* __restrict__ rowptr, const int* __restrict__ bsum, int n, int e) {
    int i = blockIdx.x * blockDim.x + threadIdx.x;
    if (i < n) rowptr[i] += bsum[i >> 10];
    if (i == 0) rowptr[n] = e;
}

__global__ void fill_kernel(const int* __restrict__ row, const int* __restrict__ col,
                            const int* __restrict__ rowptr, int* __restrict__ fillc,
                            const float* __restrict__ rnorm,
                            int2* __restrict__ meta, int e) {
    int i = blockIdx.x * blockDim.x + threadIdx.x;
    if (i >= e) return;
    int r = row[i], c = col[i];
    int pos = rowptr[r] + atomicAdd(&fillc[r], 1);
    float w = rnorm[r] * rnorm[c];
    meta[pos] = make_int2(c, __float_as_int(w));
}

__global__ void transpose_kernel(const float* __restrict__ w, float* __restrict__ wt,
                                 int dout, int din, int total) {
    int i = blockIdx.x * blockDim.x + threadIdx.x;
    if (i < total) {
        int k = i / dout, c = i % dout;   // wt[k][c] = w[c][k]
        wt[i] = w[c * din + k];
    }
}

template <int WPL> struct VecT;
template <> struct VecT<4> { using T = f32x4; };
template <> struct VecT<2> { using T = f32x2; };

// one wave per row; 64 lanes x WPL floats. Bias (+ optional gelu) fused.
// meta batches software-pipelined: next batch's metas load during current
// batch's gathers/FMAs -> dependent chain per iter is max(gather, meta)
// instead of meta + gather.
template <int WPL, bool GELU>
__global__ __launch_bounds__(256) void spmm_kernel(const float* __restrict__ in,
                                                   float* __restrict__ out,
                                                   const int* __restrict__ rowptr,
                                                   const int2* __restrict__ meta,
                                                   const float* __restrict__ rnorm,
                                                   const float* __restrict__ bias, int n) {
    using vec_t = typename VecT<WPL>::T;
    constexpr int RW = 64 * WPL;
    int wid = blockIdx.x * 4 + (threadIdx.x >> 6);
    if (wid >= n) return;
    int lane = threadIdx.x & 63;
    const float* lanebase = in + lane * WPL;

    float rn = rnorm[wid];
    float sw = rn * rn;   // self-loop weight
    float acc[WPL];
    {
        vec_t a = *(const vec_t*)(lanebase + (size_t)wid * RW);
#pragma unroll
        for (int q = 0; q < WPL; ++q) acc[q] = sw * a[q];
    }

    int e0 = rowptr[wid], e1 = rowptr[wid + 1];
    int e = e0;
    int nbatch = (e1 - e0) >> 3;
    if (nbatch > 0) {
        int2 m[8];
#pragma unroll
        for (int u = 0; u < 8; ++u) m[u] = meta[e + u];
        for (int b = 0; b < nbatch; ++b) {
            vec_t v[8];
#pragma unroll
            for (int u = 0; u < 8; ++u) v[u] = *(const vec_t*)(lanebase + (size_t)m[u].x * RW);
            int2 mn[8];
            bool more = (b + 1 < nbatch);
            if (more) {
#pragma unroll
                for (int u = 0; u < 8; ++u) mn[u] = meta[e + 8 + u];
            }
#pragma unroll
            for (int u = 0; u < 8; ++u) {
                float w = __int_as_float(m[u].y);
#pragma unroll
                for (int q = 0; q < WPL; ++q) acc[q] = fmaf(w, v[u][q], acc[q]);
            }
            if (more) {
#pragma unroll
                for (int u = 0; u < 8; ++u) m[u] = mn[u];
            }
            e += 8;
        }
    }
    for (; e < e1; ++e) {
        int2 m = meta[e];
        vec_t v = *(const vec_t*)(lanebase + (size_t)m.x * RW);
        float w = __int_as_float(m.y);
#pragma unroll
        for (int q = 0; q < WPL; ++q) acc[q] = fmaf(w, v[q], acc[q]);
    }

    vec_t bv = *(const vec_t*)(bias + lane * WPL);
    vec_t o;
#pragma unroll
    for (int q = 0; q < WPL; ++q) {
        float x = acc[q] + bv[q];
        o[q] = GELU ? gelu_fast(x) : x;
    }
    __builtin_nontemporal_store(o, (vec_t*)(out + (size_t)wid * RW + lane * WPL));
}

// dense: out[N][DO] = in[N][256] @ WT[256][DO]. No bias/gelu (fused into spmm).
// 4 waves per block PARTITION the DO columns (wave w owns cols [w*DO/4, ...)),
// so each weight row is read from L2 exactly once per block per k.
// Thread rows interleaved (tr + j*TRW) so LDS broadcast addresses hit
// distinct banks (LDR=260 -> bank stride 4 per row).
template <int DO>
__global__ __launch_bounds__(256, 4) void dense_kernel(const float* __restrict__ in,
                                                       const float* __restrict__ wt,
                                                       float* __restrict__ out) {
    constexpr int BM = 32;
    constexpr int LDR = 260;        // floats, multiple of 4 (f32x4 staging)
    constexpr int TCW = DO / 16;    // col-threads per wave: 16 (256) / 8 (128)
    constexpr int TRW = 64 / TCW;   // row-threads per wave: 4 / 8
    constexpr int RPT = BM / TRW;   // rows per thread: 8 / 4
    constexpr int WCOLS = DO / 4;   // cols per wave: 64 / 32
    __shared__ float s_in[BM * LDR];

    int t = threadIdx.x;
    int w = t >> 6;
    int lane = t & 63;
    int row0 = blockIdx.x * BM;

    // stage 32x256 input tile: coalesced nt reads, conflict-free f32x4 writes
    const f32x4* gin = (const f32x4*)(in + (size_t)row0 * 256);
#pragma unroll
    for (int i = 0; i < (BM * 64) / 256; ++i) {   // 8 iters
        int idx = t + i * 256;
        int r = idx >> 6, k4 = idx & 63;
        f32x4 val = __builtin_nontemporal_load(gin + idx);
        *(f32x4*)&s_in[r * LDR + k4 * 4] = val;
    }
    __syncthreads();

    int tc = lane % TCW;
    int tr = lane / TCW;
    int c0 = w * WCOLS + tc * 4;                    // this thread's 4 output cols
    const f32x4* wcol = (const f32x4*)wt + (c0 >> 2);  // wt[k][c0..c0+3]

    float acc[RPT][4];
#pragma unroll
    for (int j = 0; j < RPT; ++j)
#pragma unroll
        for (int q = 0; q < 4; ++q) acc[j][q] = 0.0f;

#pragma unroll 4
    for (int k = 0; k < 256; ++k) {
        f32x4 w4 = wcol[k * (DO / 4)];   // 256B/wave from L2, read once per block
#pragma unroll
        for (int j = 0; j < RPT; ++j) {
            float iv = s_in[(tr + j * TRW) * LDR + k];   // LDS broadcast, distinct banks
            acc[j][0] = fmaf(iv, w4.x, acc[j][0]);
            acc[j][1] = fmaf(iv, w4.y, acc[j][1]);
            acc[j][2] = fmaf(iv, w4.z, acc[j][2]);
            acc[j][3] = fmaf(iv, w4.w, acc[j][3]);
        }
    }

#pragma unroll
    for (int j = 0; j < RPT; ++j) {
        int r = row0 + tr + j * TRW;
        f32x4 o = { acc[j][0], acc[j][1], acc[j][2], acc[j][3] };
        *(f32x4*)&out[(size_t)r * DO + c0] = o;
    }
}

extern "C" void kernel_launch(void* const* d_in, const int* in_sizes, int n_in,
                              void* d_out, int out_size, void* d_ws, size_t ws_size,
                              hipStream_t stream) {
    const float* X  = (const float*)d_in[0];
    const int* row  = (const int*)d_in[1];
    const int* col  = (const int*)d_in[2];
    const float* W0 = (const float*)d_in[3];
    const float* b0 = (const float*)d_in[4];
    const float* W1 = (const float*)d_in[5];
    const float* b1 = (const float*)d_in[6];
    const float* W2 = (const float*)d_in[7];
    const float* b2 = (const float*)d_in[8];

    int n = in_sizes[0] / 256;   // 100000
    int e = in_sizes[1];         // 1600000

    char* ws = (char*)d_ws;
    size_t off = 0;
    auto alloc = [&](size_t bytes) {
        void* p = ws + off;
        off += (bytes + 255) & ~(size_t)255;
        return p;
    };
    float* A      = (float*)alloc((size_t)n * 256 * 4);
    float* B      = (float*)alloc((size_t)n * 256 * 4);
    float* WT0    = (float*)alloc(256 * 256 * 4);
    float* WT1    = (float*)alloc(256 * 256 * 4);
    float* WT2    = (float*)alloc(256 * 128 * 4);
    int*   cnt    = (int*)alloc((size_t)n * 4);
    int*   fillc  = (int*)alloc((size_t)n * 4);
    float* rnorm  = (float*)alloc((size_t)n * 4);
    int*   rowptr = (int*)alloc(((size_t)n + 1) * 4);
    int*   bsum   = (int*)alloc(512);
    int2*  meta   = (int2*)alloc((size_t)e * 8);

    (void)hipMemsetAsync(cnt, 0, (size_t)n * 4, stream);
    (void)hipMemsetAsync(fillc, 0, (size_t)n * 4, stream);

    int gE = (e + 255) / 256;
    int gN = (n + 255) / 256;
    int nb = (n + 1023) / 1024;

    count_kernel<<<gE, 256, 0, stream>>>(row, cnt, e);
    rnorm_kernel<<<gN, 256, 0, stream>>>(cnt, rnorm, n);
    scan1_kernel<<<nb, 1024, 0, stream>>>(cnt, rowptr, bsum, n);
    scan2_kernel<<<1, 64, 0, stream>>>(bsum, nb);
    scan3_kernel<<<gN, 256, 0, stream>>>(rowptr, bsum, n, e);
    fill_kernel<<<gE, 256, 0, stream>>>(row, col, rowptr, fillc, rnorm, meta, e);

    transpose_kernel<<<(256 * 256) / 256, 256, 0, stream>>>(W0, WT0, 256, 256, 256 * 256);
    transpose_kernel<<<(256 * 256) / 256, 256, 0, stream>>>(W1, WT1, 256, 256, 256 * 256);
    transpose_kernel<<<(256 * 128) / 256, 256, 0, stream>>>(W2, WT2, 128, 256, 256 * 128);

    int gS = (n + 3) / 4;      // spmm: 4 waves/block, 1 row/wave
    int gD = n / 32;           // dense: 32 rows/block (100000 % 32 == 0)

    // D0 = X @ W0T ; A = gelu(spmm(D0) + b0)
    dense_kernel<256><<<gD, 256, 0, stream>>>(X, WT0, A);
    spmm_kernel<4, true><<<gS, 256, 0, stream>>>(A, B, rowptr, meta, rnorm, b0, n);
    // D1 = B @ W1T ; A = gelu(spmm(D1) + b1)
    dense_kernel<256><<<gD, 256, 0, stream>>>(B, WT1, A);
    spmm_kernel<4, true><<<gS, 256, 0, stream>>>(A, B, rowptr, meta, rnorm, b1, n);
    // D2 = B @ W2T (128 wide) ; out = spmm(D2) + b2
    dense_kernel<128><<<gD, 256, 0, stream>>>(B, WT2, A);
    spmm_kernel<2, false><<<gS, 256, 0, stream>>>(A, (float*)d_out, rowptr, meta, rnorm, b2, n);
}